// Round 28
// baseline (76.206 us; speedup 1.0000x reference)
//
#include <hip/hip_runtime.h>
#include <math.h>

#define LSEQ 4096
#define DD 768
#define NST 16
#define RNK 48
#define TCH 64
#define NCH (LSEQ / TCH)   // 64 chunks
#define KSTEPS 24          // 768 / 32
#define NTILES 5           // 80 / 16
#define WFRAG_N (KSTEPS * NTILES * 64 * 8)       // 61440
#define WDTP_N  (2 * RNK * 64 * 8)               // 49152

typedef __attribute__((ext_vector_type(8))) short bf16x8;
typedef __attribute__((ext_vector_type(4))) float f32x4;

__device__ __forceinline__ float softplus_f(float z) {
    float e = __expf(-fabsf(z));
    return fmaxf(z, 0.0f) + __logf(1.0f + e);
}

__device__ __forceinline__ float tanh_fast(float w) {
    float t = __expf(2.0f * fabsf(w));
    float r = 1.0f - 2.0f / (t + 1.0f);
    return copysignf(r, w);
}

__device__ __forceinline__ float soft_clamp_f(float v) {
    const float ctr = 5.00005f;
    const float hr  = 4.99995f;
    const float inv_hr = 1.0f / 4.99995f;
    return ctr + hr * tanh_fast((v - ctr) * inv_hr);
}

__device__ __forceinline__ float wave_sum(float v) {
    #pragma unroll
    for (int m = 32; m >= 1; m >>= 1) v += __shfl_xor(v, m, 64);
    return v;
}

__device__ __forceinline__ unsigned short rne_bf16(float v) {
    unsigned u = __float_as_uint(v);
    return (unsigned short)((u + 0x7FFFu + ((u >> 16) & 1u)) >> 16);
}

// ---------------------------------------------------------------------------
// Prep: pack W=[W_dt|W_bc] (768x80) and W_dtp (48->64 padded x 768) into MFMA
// B-fragment order, bf16 hi/lo.
// ---------------------------------------------------------------------------
__global__ __launch_bounds__(256) void k_prep(
    const float* __restrict__ W_dt, const float* __restrict__ W_bc,
    const float* __restrict__ W_dtp,
    unsigned short* __restrict__ wf_hi, unsigned short* __restrict__ wf_lo,
    unsigned short* __restrict__ wp_hi, unsigned short* __restrict__ wp_lo)
{
    int i = blockIdx.x * 256 + threadIdx.x;
    if (i < WFRAG_N) {
        int j  = i & 7;
        int l  = (i >> 3) & 63;
        int nk = i >> 9;
        int n  = nk % NTILES;
        int kk = nk / NTILES;
        int k   = kk * 32 + (l >> 4) * 8 + j;
        int col = n * 16 + (l & 15);
        float v = (col < RNK) ? W_dt[k * RNK + col] : W_bc[k * 32 + (col - RNK)];
        unsigned short h = rne_bf16(v);
        float hf = __uint_as_float((unsigned)h << 16);
        wf_hi[i] = h;
        wf_lo[i] = rne_bf16(v - hf);
    } else if (i < WFRAG_N + WDTP_N) {
        int ii = i - WFRAG_N;
        int j  = ii & 7;
        int l  = (ii >> 3) & 63;
        int nk = ii >> 9;
        int n  = nk % RNK;
        int ks = nk / RNK;
        int k   = ks * 32 + (l >> 4) * 8 + j;
        int col = n * 16 + (l & 15);
        float v = (k < RNK) ? W_dtp[k * DD + col] : 0.f;
        unsigned short h = rne_bf16(v);
        float hf = __uint_as_float((unsigned)h << 16);
        wp_hi[ii] = h;
        wp_lo[ii] = rne_bf16(v - hf);
    }
}

// ---------------------------------------------------------------------------
// Fused proj v6 (R23/R26 form, best measured): phase A MFMA + phase B MFMA +
// fast RMS tail. Emits c0 = 0.5*delta, c1 = sqrt(delta)*0.5*(x_l + x_{l-1}).
// ---------------------------------------------------------------------------
__global__ __launch_bounds__(512) void k_proj_mfma(
    const float* __restrict__ x,
    const unsigned short* __restrict__ wf_hi,
    const unsigned short* __restrict__ wf_lo,
    const unsigned short* __restrict__ wp_hi,
    const unsigned short* __restrict__ wp_lo,
    const float* __restrict__ b_dt, const float* __restrict__ rms_scale,
    float* __restrict__ c0_out, float* __restrict__ c1_out,
    float* __restrict__ bc_out)
{
    __shared__ __align__(16) float smem_x[16 * 772];   // x, persistent
    __shared__ __align__(16) float smem_sp[16 * 772];  // partials, then sp
    __shared__ __align__(16) float t_lds[16][RNK];
    __shared__ float red2[8][16];

    const int tid  = threadIdx.x;
    const int lane = tid & 63;
    const int wq   = tid >> 6;
    const int mt   = blockIdx.x;

    {   // stage x (16 rows contiguous), coalesced
        const float4* xg = (const float4*)(x + (size_t)mt * 16 * DD);
        #pragma unroll 2
        for (int idx = tid; idx < 3072; idx += 512) {
            int r = idx / 192, c4 = idx - r * 192;
            *(float4*)&smem_x[r * 772 + c4 * 4] = xg[idx];
        }
    }
    __syncthreads();

    const int rloc = lane & 15;
    const int ko   = (lane >> 4) * 8;

    // ---- phase A: K split 8-way over waves ----
    f32x4 acc[NTILES];
    #pragma unroll
    for (int n = 0; n < NTILES; ++n) acc[n] = (f32x4){0.f, 0.f, 0.f, 0.f};

    #pragma unroll
    for (int k3 = 0; k3 < 3; ++k3) {
        const int kk = wq * 3 + k3;
        const float* xp = &smem_x[rloc * 772 + kk * 32 + ko];
        float4 xa = *(const float4*)xp;
        float4 xb = *(const float4*)(xp + 4);
        float va[8] = {xa.x, xa.y, xa.z, xa.w, xb.x, xb.y, xb.z, xb.w};
        bf16x8 ah, al;
        #pragma unroll
        for (int j = 0; j < 8; ++j) {
            unsigned short h = rne_bf16(va[j]);
            float hf = __uint_as_float((unsigned)h << 16);
            ah[j] = (short)h;
            al[j] = (short)rne_bf16(va[j] - hf);
        }
        const int base = kk * (NTILES * 512) + lane * 8;
        #pragma unroll
        for (int n = 0; n < NTILES; ++n) {
            bf16x8 bh = *(const bf16x8*)(wf_hi + base + n * 512);
            bf16x8 bl = *(const bf16x8*)(wf_lo + base + n * 512);
            acc[n] = __builtin_amdgcn_mfma_f32_16x16x32_bf16(al, bh, acc[n], 0, 0, 0);
            acc[n] = __builtin_amdgcn_mfma_f32_16x16x32_bf16(ah, bl, acc[n], 0, 0, 0);
            acc[n] = __builtin_amdgcn_mfma_f32_16x16x32_bf16(ah, bh, acc[n], 0, 0, 0);
        }
    }
    __syncthreads();

    if (wq > 0) {
        float* red = smem_sp + ((wq - 1) * 64 + lane) * 20;
        #pragma unroll
        for (int n = 0; n < NTILES; ++n)
            #pragma unroll
            for (int r = 0; r < 4; ++r) red[n * 4 + r] = acc[n][r];
    }
    __syncthreads();
    if (wq == 0) {
        #pragma unroll
        for (int w = 0; w < 7; ++w) {
            const float* red = smem_sp + (w * 64 + lane) * 20;
            #pragma unroll
            for (int n = 0; n < NTILES; ++n)
                #pragma unroll
                for (int r = 0; r < 4; ++r) acc[n][r] += red[n * 4 + r];
        }
        const int r0 = (lane >> 4) * 4;
        const int cb = lane & 15;
        #pragma unroll
        for (int n = 0; n < 3; ++n)
            #pragma unroll
            for (int r = 0; r < 4; ++r)
                t_lds[r0 + r][n * 16 + cb] = acc[n][r];
        #pragma unroll
        for (int n = 3; n < 5; ++n)
            #pragma unroll
            for (int r = 0; r < 4; ++r)
                bc_out[(size_t)(mt * 16 + r0 + r) * 32 + (n - 3) * 16 + cb] = acc[n][r];
    }
    __syncthreads();

    // ---- phase B (MFMA): z = t @ W_dtp -> softplus -> smem_sp ----
    bf16x8 tah[2], tal[2];
    #pragma unroll
    for (int ks = 0; ks < 2; ++ks) {
        const int kbase = ks * 32 + ko;
        float tv[8];
        #pragma unroll
        for (int j = 0; j < 8; ++j)
            tv[j] = (kbase + j < RNK) ? t_lds[rloc][kbase + j] : 0.f;
        #pragma unroll
        for (int j = 0; j < 8; ++j) {
            unsigned short h = rne_bf16(tv[j]);
            float hf = __uint_as_float((unsigned)h << 16);
            tah[ks][j] = (short)h;
            tal[ks][j] = (short)rne_bf16(tv[j] - hf);
        }
    }

    const int r0 = (lane >> 4) * 4;
    #pragma unroll
    for (int nn = 0; nn < 6; ++nn) {
        const int n = wq * 6 + nn;
        f32x4 z = (f32x4){0.f, 0.f, 0.f, 0.f};
        {
            const int b0 = n * 512 + lane * 8;
            bf16x8 bh = *(const bf16x8*)(wp_hi + b0);
            bf16x8 bl = *(const bf16x8*)(wp_lo + b0);
            z = __builtin_amdgcn_mfma_f32_16x16x32_bf16(tal[0], bh, z, 0, 0, 0);
            z = __builtin_amdgcn_mfma_f32_16x16x32_bf16(tah[0], bl, z, 0, 0, 0);
            z = __builtin_amdgcn_mfma_f32_16x16x32_bf16(tah[0], bh, z, 0, 0, 0);
        }
        {
            const int b1 = (RNK + n) * 512 + lane * 8;
            bf16x8 bh = *(const bf16x8*)(wp_hi + b1);
            bf16x8 bl = *(const bf16x8*)(wp_lo + b1);
            z = __builtin_amdgcn_mfma_f32_16x16x32_bf16(tal[1], bh, z, 0, 0, 0);
            z = __builtin_amdgcn_mfma_f32_16x16x32_bf16(tah[1], bl, z, 0, 0, 0);
            z = __builtin_amdgcn_mfma_f32_16x16x32_bf16(tah[1], bh, z, 0, 0, 0);
        }
        const int col = n * 16 + (lane & 15);
        const float bb = b_dt[col];
        #pragma unroll
        for (int r = 0; r < 4; ++r)
            smem_sp[(r0 + r) * 772 + col] = softplus_f(z[r] + bb);
    }
    __syncthreads();

    // ---- RMS tail -> c0, c1 ----
    const int d0 = tid;
    const int d1 = tid + 512;
    const bool has2 = (tid < 256);
    {
        float sp0[16], sp1[16];
        #pragma unroll
        for (int li = 0; li < 16; ++li) {
            sp0[li] = smem_sp[li * 772 + d0];
            sp1[li] = has2 ? smem_sp[li * 772 + d1] : 0.f;
        }
        #pragma unroll
        for (int li = 0; li < 16; ++li) {
            float ss = wave_sum(sp0[li] * sp0[li] + sp1[li] * sp1[li]);
            if (lane == 0) red2[wq][li] = ss;
        }
        __syncthreads();
        float rs0 = rms_scale[d0];
        float rs1 = has2 ? rms_scale[d1] : 0.f;
        float xm0 = (mt > 0) ? x[(size_t)(mt * 16 - 1) * DD + d0] : 0.f;
        float xm1 = (has2 && mt > 0) ? x[(size_t)(mt * 16 - 1) * DD + d1] : 0.f;
        #pragma unroll
        for (int li = 0; li < 16; ++li) {
            float tot = 0.f;
            #pragma unroll
            for (int k = 0; k < 8; ++k) tot += red2[k][li];
            float inv = rsqrtf(tot * (1.0f / DD) + 1e-6f);
            size_t rowoff = (size_t)(mt * 16 + li) * DD;

            float dl0 = soft_clamp_f(sp0[li] * inv * rs0);
            float xl0 = smem_x[li * 772 + d0];
            float xp0 = (li == 0) ? xm0 : smem_x[(li - 1) * 772 + d0];
            c0_out[rowoff + d0] = 0.5f * dl0;
            c1_out[rowoff + d0] = sqrtf(dl0) * 0.5f * (xl0 + xp0);

            if (has2) {
                float dl1 = soft_clamp_f(sp1[li] * inv * rs1);
                float xl1 = smem_x[li * 772 + d1];
                float xp1 = (li == 0) ? xm1 : smem_x[(li - 1) * 772 + d1];
                c0_out[rowoff + d1] = 0.5f * dl1;
                c1_out[rowoff + d1] = sqrtf(dl1) * 0.5f * (xl1 + xp1);
            }
        }
    }
}

// ---------------------------------------------------------------------------
// Scan pass 1 (TCH=64; c0/c1 staged; no x).
// ---------------------------------------------------------------------------
__global__ __launch_bounds__(256, 4) void k_scan1(
    const float* __restrict__ c0b, const float* __restrict__ c1b,
    const float* __restrict__ bc, const float* __restrict__ A_log,
    float* __restrict__ Pbuf, float* __restrict__ Hbuf)
{
    __shared__ __align__(16) float c0v[TCH * 64];
    __shared__ __align__(16) float c1v[TCH * 64];
    __shared__ __align__(16) float bs[TCH * 16];

    const int tid = threadIdx.x;
    const int db  = blockIdx.x * 64;
    const int c   = blockIdx.y;
    const int l0  = c * TCH;

    for (int i = tid; i < TCH * 16; i += 256) {
        int r = i >> 4, f = i & 15;
        *(float4*)&c0v[r * 64 + f * 4] =
            *(const float4*)&c0b[(size_t)(l0 + r) * DD + db + f * 4];
        *(float4*)&c1v[r * 64 + f * 4] =
            *(const float4*)&c1b[(size_t)(l0 + r) * DD + db + f * 4];
    }
    for (int i = tid; i < TCH * 4; i += 256) {
        int r = i >> 2, f = i & 3;
        *(float4*)&bs[r * 16 + f * 4] =
            *(const float4*)&bc[(size_t)(l0 + r) * 32 + f * 4];
    }

    const int lane = tid & 63;
    const int w    = tid >> 6;
    const int q    = lane >> 4;
    const int dlo  = (lane & 15) + w * 16;
    const int d    = db + dlo;

    float An[4];
    {
        float4 a = *(const float4*)&A_log[d * NST + q * 4];
        An[0] = -__expf(a.x); An[1] = -__expf(a.y);
        An[2] = -__expf(a.z); An[3] = -__expf(a.w);
    }
    __syncthreads();

    float h[4]  = {0.f, 0.f, 0.f, 0.f};
    float Pp[4] = {1.f, 1.f, 1.f, 1.f};

    #pragma unroll 4
    for (int ll = 0; ll < TCH; ++ll) {
        float c0 = c0v[ll * 64 + dlo];
        float c1 = c1v[ll * 64 + dlo];
        float4 Bc = *(const float4*)&bs[ll * 16 + q * 4];

        float dn0 = fmaf(-c0, An[0], 1.0f);
        float dn1 = fmaf(-c0, An[1], 1.0f);
        float dn2 = fmaf(-c0, An[2], 1.0f);
        float dn3 = fmaf(-c0, An[3], 1.0f);
        float m01 = dn0 * dn1, m23 = dn2 * dn3;
        float ip  = __builtin_amdgcn_rcpf(m01 * m23);
        float ip01 = ip * m23, ip23 = ip * m01;
        float iv0 = ip01 * dn1, iv1 = ip01 * dn0;
        float iv2 = ip23 * dn3, iv3 = ip23 * dn2;
        float t10 = 2.0f - dn0, t11 = 2.0f - dn1;
        float t12 = 2.0f - dn2, t13 = 2.0f - dn3;

        Pp[0] *= t10 * iv0;
        Pp[1] *= t11 * iv1;
        Pp[2] *= t12 * iv2;
        Pp[3] *= t13 * iv3;
        h[0] = fmaf(t10, h[0], c1 * Bc.x) * iv0;
        h[1] = fmaf(t11, h[1], c1 * Bc.y) * iv1;
        h[2] = fmaf(t12, h[2], c1 * Bc.z) * iv2;
        h[3] = fmaf(t13, h[3], c1 * Bc.w) * iv3;
    }
    #pragma unroll
    for (int n = 0; n < 4; ++n) {
        int idx = (c * NST + q * 4 + n) * DD + d;
        Pbuf[idx] = Pp[n];
        Hbuf[idx] = h[n];
    }
}

// ---------------------------------------------------------------------------
// Scan pass 2: serial thread-per-series, coalesced, 8-deep prefetch.
// ---------------------------------------------------------------------------
__global__ __launch_bounds__(64) void k_scan2(
    float* __restrict__ Pbuf, const float* __restrict__ Hbuf)
{
    const int s = blockIdx.x * 64 + threadIdx.x;
    const int d = s % DD;
    const int n = s / DD;
    const int stride = NST * DD;

    int idx = n * DD + d;
    int idx_pf = idx;
    float p[8], h[8];
    #pragma unroll
    for (int i = 0; i < 8; ++i) {
        p[i] = Pbuf[idx_pf];
        h[i] = Hbuf[idx_pf];
        idx_pf += stride;
    }

    float carry = 0.f;
    for (int g = 0; g < NCH / 8; ++g) {
        float pn[8], hn[8];
        if (g + 1 < NCH / 8) {
            #pragma unroll
            for (int i = 0; i < 8; ++i) {
                pn[i] = Pbuf[idx_pf];
                hn[i] = Hbuf[idx_pf];
                idx_pf += stride;
            }
        }
        #pragma unroll
        for (int i = 0; i < 8; ++i) {
            Pbuf[idx] = carry;
            carry = fmaf(p[i], carry, h[i]);
            idx += stride;
        }
        #pragma unroll
        for (int i = 0; i < 8; ++i) { p[i] = pn[i]; h[i] = hn[i]; }
    }
}

// ---------------------------------------------------------------------------
// Scan pass 3 (TCH=64; c0/c1 staged; rolling nontemporal x prefetch;
// nontemporal out).
// ---------------------------------------------------------------------------
__global__ __launch_bounds__(256, 4) void k_scan3(
    const float* __restrict__ x, const float* __restrict__ c0b,
    const float* __restrict__ c1b, const float* __restrict__ bc,
    const float* __restrict__ A_log, const float* __restrict__ carryin,
    const float* __restrict__ D_param, float* __restrict__ out)
{
    __shared__ __align__(16) float c0v[TCH * 64];
    __shared__ __align__(16) float c1v[TCH * 64];
    __shared__ __align__(16) float bs[TCH * 32];

    const int tid = threadIdx.x;
    const int db  = blockIdx.x * 64;
    const int c   = blockIdx.y;
    const int l0  = c * TCH;

    for (int i = tid; i < TCH * 16; i += 256) {
        int r = i >> 4, f = i & 15;
        *(float4*)&c0v[r * 64 + f * 4] =
            *(const float4*)&c0b[(size_t)(l0 + r) * DD + db + f * 4];
        *(float4*)&c1v[r * 64 + f * 4] =
            *(const float4*)&c1b[(size_t)(l0 + r) * DD + db + f * 4];
    }
    for (int i = tid; i < TCH * 8; i += 256) {
        int r = i >> 3, f = i & 7;
        *(float4*)&bs[r * 32 + f * 4] =
            *(const float4*)&bc[(size_t)(l0 + r) * 32 + f * 4];
    }

    const int lane = tid & 63;
    const int w    = tid >> 6;
    const int q    = lane >> 4;
    const int dlo  = (lane & 15) + w * 16;
    const int d    = db + dlo;

    float An[4];
    {
        float4 a = *(const float4*)&A_log[d * NST + q * 4];
        An[0] = -__expf(a.x); An[1] = -__expf(a.y);
        An[2] = -__expf(a.z); An[3] = -__expf(a.w);
    }
    float h[4];
    #pragma unroll
    for (int n = 0; n < 4; ++n)
        h[n] = carryin[(c * NST + q * 4 + n) * DD + d];
    const float Dp = D_param[d];

    __syncthreads();

    float xv_n = __builtin_nontemporal_load(&x[(size_t)l0 * DD + d]);
    #pragma unroll 4
    for (int ll = 0; ll < TCH; ++ll) {
        float xv = xv_n;
        const int lnx = (l0 + ll + 1 < LSEQ) ? l0 + ll + 1 : l0 + ll;
        xv_n = __builtin_nontemporal_load(&x[(size_t)lnx * DD + d]);

        float c0 = c0v[ll * 64 + dlo];
        float c1 = c1v[ll * 64 + dlo];
        float4 Bc = *(const float4*)&bs[ll * 32 + q * 4];
        float4 Cc = *(const float4*)&bs[ll * 32 + 16 + q * 4];

        float dn0 = fmaf(-c0, An[0], 1.0f);
        float dn1 = fmaf(-c0, An[1], 1.0f);
        float dn2 = fmaf(-c0, An[2], 1.0f);
        float dn3 = fmaf(-c0, An[3], 1.0f);
        float m01 = dn0 * dn1, m23 = dn2 * dn3;
        float ip  = __builtin_amdgcn_rcpf(m01 * m23);
        float ip01 = ip * m23, ip23 = ip * m01;
        float iv0 = ip01 * dn1, iv1 = ip01 * dn0;
        float iv2 = ip23 * dn3, iv3 = ip23 * dn2;
        float t10 = 2.0f - dn0, t11 = 2.0f - dn1;
        float t12 = 2.0f - dn2, t13 = 2.0f - dn3;

        h[0] = fmaf(t10, h[0], c1 * Bc.x) * iv0;
        h[1] = fmaf(t11, h[1], c1 * Bc.y) * iv1;
        h[2] = fmaf(t12, h[2], c1 * Bc.z) * iv2;
        h[3] = fmaf(t13, h[3], c1 * Bc.w) * iv3;

        float y = h[0] * Cc.x;
        y = fmaf(h[1], Cc.y, y);
        y = fmaf(h[2], Cc.z, y);
        y = fmaf(h[3], Cc.w, y);

        y += __shfl_xor(y, 16, 64);
        y += __shfl_xor(y, 32, 64);
        if (q == 0)
            __builtin_nontemporal_store(fmaf(Dp, xv, y),
                                        &out[(size_t)(l0 + ll) * DD + d]);
    }
}

extern "C" void kernel_launch(void* const* d_in, const int* in_sizes, int n_in,
                              void* d_out, int out_size, void* d_ws, size_t ws_size,
                              hipStream_t stream) {
    const float* x         = (const float*)d_in[0];
    const float* A_log     = (const float*)d_in[1];
    const float* D_param   = (const float*)d_in[2];
    const float* W_bc      = (const float*)d_in[3];
    const float* W_dt      = (const float*)d_in[4];
    const float* W_dtp     = (const float*)d_in[5];
    const float* b_dt      = (const float*)d_in[6];
    const float* rms_scale = (const float*)d_in[7];
    float* out = (float*)d_out;

    float* ws    = (float*)d_ws;
    float* c0buf = ws;                               // L*D
    float* c1buf = c0buf + (size_t)LSEQ * DD;        // L*D
    float* bcbuf = c1buf + (size_t)LSEQ * DD;        // L*32
    float* Pbuf  = bcbuf + (size_t)LSEQ * 32;        // NCH*16*D
    float* Hbuf  = Pbuf + (size_t)NCH * NST * DD;    // NCH*16*D
    unsigned short* wf_hi = (unsigned short*)(Hbuf + (size_t)NCH * NST * DD);
    unsigned short* wf_lo = wf_hi + WFRAG_N;
    unsigned short* wp_hi = wf_lo + WFRAG_N;
    unsigned short* wp_lo = wp_hi + WDTP_N;

    k_prep<<<(WFRAG_N + WDTP_N + 255) / 256, 256, 0, stream>>>(
        W_dt, W_bc, W_dtp, wf_hi, wf_lo, wp_hi, wp_lo);
    k_proj_mfma<<<LSEQ / 16, 512, 0, stream>>>(x, wf_hi, wf_lo, wp_hi, wp_lo,
                                               b_dt, rms_scale, c0buf, c1buf,
                                               bcbuf);
    k_scan1<<<dim3(DD / 64, NCH), 256, 0, stream>>>(c0buf, c1buf, bcbuf, A_log,
                                                    Pbuf, Hbuf);
    k_scan2<<<(DD * NST) / 64, 64, 0, stream>>>(Pbuf, Hbuf);
    k_scan3<<<dim3(DD / 64, NCH), 256, 0, stream>>>(x, c0buf, c1buf, bcbuf,
                                                    A_log, Pbuf, D_param, out);
}

// Round 29
// 73.617 us; speedup vs baseline: 1.0352x; 1.0352x over previous
//
#include <hip/hip_runtime.h>
#include <math.h>

#define LSEQ 4096
#define DD 768
#define NST 16
#define RNK 48
#define TCH 64
#define NCH (LSEQ / TCH)   // 64 chunks
#define KSTEPS 24          // 768 / 32
#define NTILES 5           // 80 / 16
#define WFRAG_N (KSTEPS * NTILES * 64 * 8)       // 61440
#define WDTP_N  (2 * RNK * 64 * 8)               // 49152

typedef __attribute__((ext_vector_type(8))) short bf16x8;
typedef __attribute__((ext_vector_type(4))) float f32x4;

__device__ __forceinline__ float softplus_f(float z) {
    float e = __expf(-fabsf(z));
    return fmaxf(z, 0.0f) + __logf(1.0f + e);
}

__device__ __forceinline__ float tanh_fast(float w) {
    float t = __expf(2.0f * fabsf(w));
    float r = 1.0f - 2.0f / (t + 1.0f);
    return copysignf(r, w);
}

__device__ __forceinline__ float soft_clamp_f(float v) {
    const float ctr = 5.00005f;
    const float hr  = 4.99995f;
    const float inv_hr = 1.0f / 4.99995f;
    return ctr + hr * tanh_fast((v - ctr) * inv_hr);
}

__device__ __forceinline__ float wave_sum(float v) {
    #pragma unroll
    for (int m = 32; m >= 1; m >>= 1) v += __shfl_xor(v, m, 64);
    return v;
}

__device__ __forceinline__ unsigned short rne_bf16(float v) {
    unsigned u = __float_as_uint(v);
    return (unsigned short)((u + 0x7FFFu + ((u >> 16) & 1u)) >> 16);
}

// ---------------------------------------------------------------------------
// Prep: pack W=[W_dt|W_bc] (768x80) and W_dtp (48->64 padded x 768) into MFMA
// B-fragment order, bf16 hi/lo.
// ---------------------------------------------------------------------------
__global__ __launch_bounds__(256) void k_prep(
    const float* __restrict__ W_dt, const float* __restrict__ W_bc,
    const float* __restrict__ W_dtp,
    unsigned short* __restrict__ wf_hi, unsigned short* __restrict__ wf_lo,
    unsigned short* __restrict__ wp_hi, unsigned short* __restrict__ wp_lo)
{
    int i = blockIdx.x * 256 + threadIdx.x;
    if (i < WFRAG_N) {
        int j  = i & 7;
        int l  = (i >> 3) & 63;
        int nk = i >> 9;
        int n  = nk % NTILES;
        int kk = nk / NTILES;
        int k   = kk * 32 + (l >> 4) * 8 + j;
        int col = n * 16 + (l & 15);
        float v = (col < RNK) ? W_dt[k * RNK + col] : W_bc[k * 32 + (col - RNK)];
        unsigned short h = rne_bf16(v);
        float hf = __uint_as_float((unsigned)h << 16);
        wf_hi[i] = h;
        wf_lo[i] = rne_bf16(v - hf);
    } else if (i < WFRAG_N + WDTP_N) {
        int ii = i - WFRAG_N;
        int j  = ii & 7;
        int l  = (ii >> 3) & 63;
        int nk = ii >> 9;
        int n  = nk % RNK;
        int ks = nk / RNK;
        int k   = ks * 32 + (l >> 4) * 8 + j;
        int col = n * 16 + (l & 15);
        float v = (k < RNK) ? W_dtp[k * DD + col] : 0.f;
        unsigned short h = rne_bf16(v);
        float hf = __uint_as_float((unsigned)h << 16);
        wp_hi[ii] = h;
        wp_lo[ii] = rne_bf16(v - hf);
    }
}

// ---------------------------------------------------------------------------
// Fused proj v6 (R23/R26 form, best measured): phase A MFMA + phase B MFMA +
// fast RMS tail. Emits c0 = 0.5*delta, c1 = sqrt(delta)*0.5*(x_l + x_{l-1}).
// ---------------------------------------------------------------------------
__global__ __launch_bounds__(512) void k_proj_mfma(
    const float* __restrict__ x,
    const unsigned short* __restrict__ wf_hi,
    const unsigned short* __restrict__ wf_lo,
    const unsigned short* __restrict__ wp_hi,
    const unsigned short* __restrict__ wp_lo,
    const float* __restrict__ b_dt, const float* __restrict__ rms_scale,
    float* __restrict__ c0_out, float* __restrict__ c1_out,
    float* __restrict__ bc_out)
{
    __shared__ __align__(16) float smem_x[16 * 772];   // x, persistent
    __shared__ __align__(16) float smem_sp[16 * 772];  // partials, then sp
    __shared__ __align__(16) float t_lds[16][RNK];
    __shared__ float red2[8][16];

    const int tid  = threadIdx.x;
    const int lane = tid & 63;
    const int wq   = tid >> 6;
    const int mt   = blockIdx.x;

    {   // stage x (16 rows contiguous), coalesced
        const float4* xg = (const float4*)(x + (size_t)mt * 16 * DD);
        #pragma unroll 2
        for (int idx = tid; idx < 3072; idx += 512) {
            int r = idx / 192, c4 = idx - r * 192;
            *(float4*)&smem_x[r * 772 + c4 * 4] = xg[idx];
        }
    }
    __syncthreads();

    const int rloc = lane & 15;
    const int ko   = (lane >> 4) * 8;

    // ---- phase A: K split 8-way over waves ----
    f32x4 acc[NTILES];
    #pragma unroll
    for (int n = 0; n < NTILES; ++n) acc[n] = (f32x4){0.f, 0.f, 0.f, 0.f};

    #pragma unroll
    for (int k3 = 0; k3 < 3; ++k3) {
        const int kk = wq * 3 + k3;
        const float* xp = &smem_x[rloc * 772 + kk * 32 + ko];
        float4 xa = *(const float4*)xp;
        float4 xb = *(const float4*)(xp + 4);
        float va[8] = {xa.x, xa.y, xa.z, xa.w, xb.x, xb.y, xb.z, xb.w};
        bf16x8 ah, al;
        #pragma unroll
        for (int j = 0; j < 8; ++j) {
            unsigned short h = rne_bf16(va[j]);
            float hf = __uint_as_float((unsigned)h << 16);
            ah[j] = (short)h;
            al[j] = (short)rne_bf16(va[j] - hf);
        }
        const int base = kk * (NTILES * 512) + lane * 8;
        #pragma unroll
        for (int n = 0; n < NTILES; ++n) {
            bf16x8 bh = *(const bf16x8*)(wf_hi + base + n * 512);
            bf16x8 bl = *(const bf16x8*)(wf_lo + base + n * 512);
            acc[n] = __builtin_amdgcn_mfma_f32_16x16x32_bf16(al, bh, acc[n], 0, 0, 0);
            acc[n] = __builtin_amdgcn_mfma_f32_16x16x32_bf16(ah, bl, acc[n], 0, 0, 0);
            acc[n] = __builtin_amdgcn_mfma_f32_16x16x32_bf16(ah, bh, acc[n], 0, 0, 0);
        }
    }
    __syncthreads();

    if (wq > 0) {
        float* red = smem_sp + ((wq - 1) * 64 + lane) * 20;
        #pragma unroll
        for (int n = 0; n < NTILES; ++n)
            #pragma unroll
            for (int r = 0; r < 4; ++r) red[n * 4 + r] = acc[n][r];
    }
    __syncthreads();
    if (wq == 0) {
        #pragma unroll
        for (int w = 0; w < 7; ++w) {
            const float* red = smem_sp + (w * 64 + lane) * 20;
            #pragma unroll
            for (int n = 0; n < NTILES; ++n)
                #pragma unroll
                for (int r = 0; r < 4; ++r) acc[n][r] += red[n * 4 + r];
        }
        const int r0 = (lane >> 4) * 4;
        const int cb = lane & 15;
        #pragma unroll
        for (int n = 0; n < 3; ++n)
            #pragma unroll
            for (int r = 0; r < 4; ++r)
                t_lds[r0 + r][n * 16 + cb] = acc[n][r];
        #pragma unroll
        for (int n = 3; n < 5; ++n)
            #pragma unroll
            for (int r = 0; r < 4; ++r)
                bc_out[(size_t)(mt * 16 + r0 + r) * 32 + (n - 3) * 16 + cb] = acc[n][r];
    }
    __syncthreads();

    // ---- phase B (MFMA): z = t @ W_dtp -> softplus -> smem_sp ----
    bf16x8 tah[2], tal[2];
    #pragma unroll
    for (int ks = 0; ks < 2; ++ks) {
        const int kbase = ks * 32 + ko;
        float tv[8];
        #pragma unroll
        for (int j = 0; j < 8; ++j)
            tv[j] = (kbase + j < RNK) ? t_lds[rloc][kbase + j] : 0.f;
        #pragma unroll
        for (int j = 0; j < 8; ++j) {
            unsigned short h = rne_bf16(tv[j]);
            float hf = __uint_as_float((unsigned)h << 16);
            tah[ks][j] = (short)h;
            tal[ks][j] = (short)rne_bf16(tv[j] - hf);
        }
    }

    const int r0 = (lane >> 4) * 4;
    #pragma unroll
    for (int nn = 0; nn < 6; ++nn) {
        const int n = wq * 6 + nn;
        f32x4 z = (f32x4){0.f, 0.f, 0.f, 0.f};
        {
            const int b0 = n * 512 + lane * 8;
            bf16x8 bh = *(const bf16x8*)(wp_hi + b0);
            bf16x8 bl = *(const bf16x8*)(wp_lo + b0);
            z = __builtin_amdgcn_mfma_f32_16x16x32_bf16(tal[0], bh, z, 0, 0, 0);
            z = __builtin_amdgcn_mfma_f32_16x16x32_bf16(tah[0], bl, z, 0, 0, 0);
            z = __builtin_amdgcn_mfma_f32_16x16x32_bf16(tah[0], bh, z, 0, 0, 0);
        }
        {
            const int b1 = (RNK + n) * 512 + lane * 8;
            bf16x8 bh = *(const bf16x8*)(wp_hi + b1);
            bf16x8 bl = *(const bf16x8*)(wp_lo + b1);
            z = __builtin_amdgcn_mfma_f32_16x16x32_bf16(tal[1], bh, z, 0, 0, 0);
            z = __builtin_amdgcn_mfma_f32_16x16x32_bf16(tah[1], bl, z, 0, 0, 0);
            z = __builtin_amdgcn_mfma_f32_16x16x32_bf16(tah[1], bh, z, 0, 0, 0);
        }
        const int col = n * 16 + (lane & 15);
        const float bb = b_dt[col];
        #pragma unroll
        for (int r = 0; r < 4; ++r)
            smem_sp[(r0 + r) * 772 + col] = softplus_f(z[r] + bb);
    }
    __syncthreads();

    // ---- RMS tail -> c0, c1 ----
    const int d0 = tid;
    const int d1 = tid + 512;
    const bool has2 = (tid < 256);
    {
        float sp0[16], sp1[16];
        #pragma unroll
        for (int li = 0; li < 16; ++li) {
            sp0[li] = smem_sp[li * 772 + d0];
            sp1[li] = has2 ? smem_sp[li * 772 + d1] : 0.f;
        }
        #pragma unroll
        for (int li = 0; li < 16; ++li) {
            float ss = wave_sum(sp0[li] * sp0[li] + sp1[li] * sp1[li]);
            if (lane == 0) red2[wq][li] = ss;
        }
        __syncthreads();
        float rs0 = rms_scale[d0];
        float rs1 = has2 ? rms_scale[d1] : 0.f;
        float xm0 = (mt > 0) ? x[(size_t)(mt * 16 - 1) * DD + d0] : 0.f;
        float xm1 = (has2 && mt > 0) ? x[(size_t)(mt * 16 - 1) * DD + d1] : 0.f;
        #pragma unroll
        for (int li = 0; li < 16; ++li) {
            float tot = 0.f;
            #pragma unroll
            for (int k = 0; k < 8; ++k) tot += red2[k][li];
            float inv = rsqrtf(tot * (1.0f / DD) + 1e-6f);
            size_t rowoff = (size_t)(mt * 16 + li) * DD;

            float dl0 = soft_clamp_f(sp0[li] * inv * rs0);
            float xl0 = smem_x[li * 772 + d0];
            float xp0 = (li == 0) ? xm0 : smem_x[(li - 1) * 772 + d0];
            c0_out[rowoff + d0] = 0.5f * dl0;
            c1_out[rowoff + d0] = sqrtf(dl0) * 0.5f * (xl0 + xp0);

            if (has2) {
                float dl1 = soft_clamp_f(sp1[li] * inv * rs1);
                float xl1 = smem_x[li * 772 + d1];
                float xp1 = (li == 0) ? xm1 : smem_x[(li - 1) * 772 + d1];
                c0_out[rowoff + d1] = 0.5f * dl1;
                c1_out[rowoff + d1] = sqrtf(dl1) * 0.5f * (xl1 + xp1);
            }
        }
    }
}

// ---------------------------------------------------------------------------
// Scan pass 1 (TCH=64; c0/c1 staged; no x).
// ---------------------------------------------------------------------------
__global__ __launch_bounds__(256, 4) void k_scan1(
    const float* __restrict__ c0b, const float* __restrict__ c1b,
    const float* __restrict__ bc, const float* __restrict__ A_log,
    float* __restrict__ Pbuf, float* __restrict__ Hbuf)
{
    __shared__ __align__(16) float c0v[TCH * 64];
    __shared__ __align__(16) float c1v[TCH * 64];
    __shared__ __align__(16) float bs[TCH * 16];

    const int tid = threadIdx.x;
    const int db  = blockIdx.x * 64;
    const int c   = blockIdx.y;
    const int l0  = c * TCH;

    for (int i = tid; i < TCH * 16; i += 256) {
        int r = i >> 4, f = i & 15;
        *(float4*)&c0v[r * 64 + f * 4] =
            *(const float4*)&c0b[(size_t)(l0 + r) * DD + db + f * 4];
        *(float4*)&c1v[r * 64 + f * 4] =
            *(const float4*)&c1b[(size_t)(l0 + r) * DD + db + f * 4];
    }
    for (int i = tid; i < TCH * 4; i += 256) {
        int r = i >> 2, f = i & 3;
        *(float4*)&bs[r * 16 + f * 4] =
            *(const float4*)&bc[(size_t)(l0 + r) * 32 + f * 4];
    }

    const int lane = tid & 63;
    const int w    = tid >> 6;
    const int q    = lane >> 4;
    const int dlo  = (lane & 15) + w * 16;
    const int d    = db + dlo;

    float An[4];
    {
        float4 a = *(const float4*)&A_log[d * NST + q * 4];
        An[0] = -__expf(a.x); An[1] = -__expf(a.y);
        An[2] = -__expf(a.z); An[3] = -__expf(a.w);
    }
    __syncthreads();

    float h[4]  = {0.f, 0.f, 0.f, 0.f};
    float Pp[4] = {1.f, 1.f, 1.f, 1.f};

    #pragma unroll 4
    for (int ll = 0; ll < TCH; ++ll) {
        float c0 = c0v[ll * 64 + dlo];
        float c1 = c1v[ll * 64 + dlo];
        float4 Bc = *(const float4*)&bs[ll * 16 + q * 4];

        float dn0 = fmaf(-c0, An[0], 1.0f);
        float dn1 = fmaf(-c0, An[1], 1.0f);
        float dn2 = fmaf(-c0, An[2], 1.0f);
        float dn3 = fmaf(-c0, An[3], 1.0f);
        float m01 = dn0 * dn1, m23 = dn2 * dn3;
        float ip  = __builtin_amdgcn_rcpf(m01 * m23);
        float ip01 = ip * m23, ip23 = ip * m01;
        float iv0 = ip01 * dn1, iv1 = ip01 * dn0;
        float iv2 = ip23 * dn3, iv3 = ip23 * dn2;
        float t10 = 2.0f - dn0, t11 = 2.0f - dn1;
        float t12 = 2.0f - dn2, t13 = 2.0f - dn3;

        Pp[0] *= t10 * iv0;
        Pp[1] *= t11 * iv1;
        Pp[2] *= t12 * iv2;
        Pp[3] *= t13 * iv3;
        h[0] = fmaf(t10, h[0], c1 * Bc.x) * iv0;
        h[1] = fmaf(t11, h[1], c1 * Bc.y) * iv1;
        h[2] = fmaf(t12, h[2], c1 * Bc.z) * iv2;
        h[3] = fmaf(t13, h[3], c1 * Bc.w) * iv3;
    }
    #pragma unroll
    for (int n = 0; n < 4; ++n) {
        int idx = (c * NST + q * 4 + n) * DD + d;
        Pbuf[idx] = Pp[n];
        Hbuf[idx] = h[n];
    }
}

// ---------------------------------------------------------------------------
// Scan pass 2: serial thread-per-series, coalesced, 8-deep prefetch.
// ---------------------------------------------------------------------------
__global__ __launch_bounds__(64) void k_scan2(
    float* __restrict__ Pbuf, const float* __restrict__ Hbuf)
{
    const int s = blockIdx.x * 64 + threadIdx.x;
    const int d = s % DD;
    const int n = s / DD;
    const int stride = NST * DD;

    int idx = n * DD + d;
    int idx_pf = idx;
    float p[8], h[8];
    #pragma unroll
    for (int i = 0; i < 8; ++i) {
        p[i] = Pbuf[idx_pf];
        h[i] = Hbuf[idx_pf];
        idx_pf += stride;
    }

    float carry = 0.f;
    for (int g = 0; g < NCH / 8; ++g) {
        float pn[8], hn[8];
        if (g + 1 < NCH / 8) {
            #pragma unroll
            for (int i = 0; i < 8; ++i) {
                pn[i] = Pbuf[idx_pf];
                hn[i] = Hbuf[idx_pf];
                idx_pf += stride;
            }
        }
        #pragma unroll
        for (int i = 0; i < 8; ++i) {
            Pbuf[idx] = carry;
            carry = fmaf(p[i], carry, h[i]);
            idx += stride;
        }
        #pragma unroll
        for (int i = 0; i < 8; ++i) { p[i] = pn[i]; h[i] = hn[i]; }
    }
}

// ---------------------------------------------------------------------------
// Scan pass 3 (TCH=64; c0/c1 staged; rolling x prefetch; nontemporal out).
// ---------------------------------------------------------------------------
__global__ __launch_bounds__(256, 4) void k_scan3(
    const float* __restrict__ x, const float* __restrict__ c0b,
    const float* __restrict__ c1b, const float* __restrict__ bc,
    const float* __restrict__ A_log, const float* __restrict__ carryin,
    const float* __restrict__ D_param, float* __restrict__ out)
{
    __shared__ __align__(16) float c0v[TCH * 64];
    __shared__ __align__(16) float c1v[TCH * 64];
    __shared__ __align__(16) float bs[TCH * 32];

    const int tid = threadIdx.x;
    const int db  = blockIdx.x * 64;
    const int c   = blockIdx.y;
    const int l0  = c * TCH;

    for (int i = tid; i < TCH * 16; i += 256) {
        int r = i >> 4, f = i & 15;
        *(float4*)&c0v[r * 64 + f * 4] =
            *(const float4*)&c0b[(size_t)(l0 + r) * DD + db + f * 4];
        *(float4*)&c1v[r * 64 + f * 4] =
            *(const float4*)&c1b[(size_t)(l0 + r) * DD + db + f * 4];
    }
    for (int i = tid; i < TCH * 8; i += 256) {
        int r = i >> 3, f = i & 7;
        *(float4*)&bs[r * 32 + f * 4] =
            *(const float4*)&bc[(size_t)(l0 + r) * 32 + f * 4];
    }

    const int lane = tid & 63;
    const int w    = tid >> 6;
    const int q    = lane >> 4;
    const int dlo  = (lane & 15) + w * 16;
    const int d    = db + dlo;

    float An[4];
    {
        float4 a = *(const float4*)&A_log[d * NST + q * 4];
        An[0] = -__expf(a.x); An[1] = -__expf(a.y);
        An[2] = -__expf(a.z); An[3] = -__expf(a.w);
    }
    float h[4];
    #pragma unroll
    for (int n = 0; n < 4; ++n)
        h[n] = carryin[(c * NST + q * 4 + n) * DD + d];
    const float Dp = D_param[d];

    __syncthreads();

    float xv_n = x[(size_t)l0 * DD + d];
    #pragma unroll 4
    for (int ll = 0; ll < TCH; ++ll) {
        float xv = xv_n;
        const int lnx = (l0 + ll + 1 < LSEQ) ? l0 + ll + 1 : l0 + ll;
        xv_n = x[(size_t)lnx * DD + d];

        float c0 = c0v[ll * 64 + dlo];
        float c1 = c1v[ll * 64 + dlo];
        float4 Bc = *(const float4*)&bs[ll * 32 + q * 4];
        float4 Cc = *(const float4*)&bs[ll * 32 + 16 + q * 4];

        float dn0 = fmaf(-c0, An[0], 1.0f);
        float dn1 = fmaf(-c0, An[1], 1.0f);
        float dn2 = fmaf(-c0, An[2], 1.0f);
        float dn3 = fmaf(-c0, An[3], 1.0f);
        float m01 = dn0 * dn1, m23 = dn2 * dn3;
        float ip  = __builtin_amdgcn_rcpf(m01 * m23);
        float ip01 = ip * m23, ip23 = ip * m01;
        float iv0 = ip01 * dn1, iv1 = ip01 * dn0;
        float iv2 = ip23 * dn3, iv3 = ip23 * dn2;
        float t10 = 2.0f - dn0, t11 = 2.0f - dn1;
        float t12 = 2.0f - dn2, t13 = 2.0f - dn3;

        h[0] = fmaf(t10, h[0], c1 * Bc.x) * iv0;
        h[1] = fmaf(t11, h[1], c1 * Bc.y) * iv1;
        h[2] = fmaf(t12, h[2], c1 * Bc.z) * iv2;
        h[3] = fmaf(t13, h[3], c1 * Bc.w) * iv3;

        float y = h[0] * Cc.x;
        y = fmaf(h[1], Cc.y, y);
        y = fmaf(h[2], Cc.z, y);
        y = fmaf(h[3], Cc.w, y);

        y += __shfl_xor(y, 16, 64);
        y += __shfl_xor(y, 32, 64);
        if (q == 0)
            __builtin_nontemporal_store(fmaf(Dp, xv, y),
                                        &out[(size_t)(l0 + ll) * DD + d]);
    }
}

extern "C" void kernel_launch(void* const* d_in, const int* in_sizes, int n_in,
                              void* d_out, int out_size, void* d_ws, size_t ws_size,
                              hipStream_t stream) {
    const float* x         = (const float*)d_in[0];
    const float* A_log     = (const float*)d_in[1];
    const float* D_param   = (const float*)d_in[2];
    const float* W_bc      = (const float*)d_in[3];
    const float* W_dt      = (const float*)d_in[4];
    const float* W_dtp     = (const float*)d_in[5];
    const float* b_dt      = (const float*)d_in[6];
    const float* rms_scale = (const float*)d_in[7];
    float* out = (float*)d_out;

    float* ws    = (float*)d_ws;
    float* c0buf = ws;                               // L*D
    float* c1buf = c0buf + (size_t)LSEQ * DD;        // L*D
    float* bcbuf = c1buf + (size_t)LSEQ * DD;        // L*32
    float* Pbuf  = bcbuf + (size_t)LSEQ * 32;        // NCH*16*D
    float* Hbuf  = Pbuf + (size_t)NCH * NST * DD;    // NCH*16*D
    unsigned short* wf_hi = (unsigned short*)(Hbuf + (size_t)NCH * NST * DD);
    unsigned short* wf_lo = wf_hi + WFRAG_N;
    unsigned short* wp_hi = wf_lo + WFRAG_N;
    unsigned short* wp_lo = wp_hi + WDTP_N;

    k_prep<<<(WFRAG_N + WDTP_N + 255) / 256, 256, 0, stream>>>(
        W_dt, W_bc, W_dtp, wf_hi, wf_lo, wp_hi, wp_lo);
    k_proj_mfma<<<LSEQ / 16, 512, 0, stream>>>(x, wf_hi, wf_lo, wp_hi, wp_lo,
                                               b_dt, rms_scale, c0buf, c1buf,
                                               bcbuf);
    k_scan1<<<dim3(DD / 64, NCH), 256, 0, stream>>>(c0buf, c1buf, bcbuf, A_log,
                                                    Pbuf, Hbuf);
    k_scan2<<<(DD * NST) / 64, 64, 0, stream>>>(Pbuf, Hbuf);
    k_scan3<<<dim3(DD / 64, NCH), 256, 0, stream>>>(x, c0buf, c1buf, bcbuf,
                                                    A_log, Pbuf, D_param, out);
}